// Round 10
// baseline (348.581 us; speedup 1.0000x reference)
//
#include <hip/hip_runtime.h>
#include <hip/hip_bf16.h>

typedef unsigned short u16;
typedef __attribute__((ext_vector_type(8))) short short8;   // 8 x bf16 bits
typedef __attribute__((ext_vector_type(4))) short short4v;  // 4 x bf16 bits
typedef __attribute__((ext_vector_type(4))) float f32x4;

#define S_DIM 2048
#define D_DIM 2048
#define H_NUM 16
#define DH_NUM 64

#if __has_builtin(__builtin_amdgcn_exp2f)
#define EXP2(x) __builtin_amdgcn_exp2f(x)
#else
#define EXP2(x) exp2f(x)
#endif

__device__ __forceinline__ u16 f2bf(float f) {
    union { float f; unsigned u; } x; x.f = f;
    unsigned r = x.u + 0x7fff + ((x.u >> 16) & 1);   // RNE
    return (u16)(r >> 16);
}

// pack 2 fp32 -> 2 bf16 (RNE) in one v_cvt_pk_bf16_f32
__device__ __forceinline__ unsigned pk_bf16(float a, float b) {
    union { __hip_bfloat162 h; unsigned u; } cv;
    float2 t; t.x = a; t.y = b;
    cv.h = __float22bfloat162_rn(t);
    return cv.u;
}

// async global->LDS, 16B per lane; LDS dest = wave-uniform base + lane*16
__device__ __forceinline__ void gload16(const void* g, void* l) {
    __builtin_amdgcn_global_load_lds(
        (const __attribute__((address_space(1))) unsigned int*)g,
        (__attribute__((address_space(3))) unsigned int*)l, 16, 0, 0);
}

// ---------------------------------------------------------------------------
// Fast transpose body: 64x64 fp32 LDS tile, float4 reads, 16B bf16 stores.
// ---------------------------------------------------------------------------
__device__ __forceinline__ void transpose_body(const float* __restrict__ src,
                                               u16* __restrict__ dst,
                                               int tx, int ty, int t)
{
    __shared__ float tile[64][65];
    const int r0 = ty * 64, c0 = tx * 64;
#pragma unroll
    for (int p = 0; p < 4; ++p) {
        int r = p * 16 + (t >> 4), c = (t & 15) * 4;
        float4 v = *(const float4*)&src[(long)(r0 + r) * D_DIM + c0 + c];
        tile[r][c] = v.x; tile[r][c + 1] = v.y;
        tile[r][c + 2] = v.z; tile[r][c + 3] = v.w;
    }
    __syncthreads();
#pragma unroll
    for (int p = 0; p < 2; ++p) {
        int ch = t + p * 256;
        int i = ch >> 3, j0 = (ch & 7) * 8;
        short8 o;
#pragma unroll
        for (int jj = 0; jj < 8; ++jj)
            o[jj] = (short)f2bf(tile[j0 + jj][i]);
        *(short8*)&dst[(long)(c0 + i) * D_DIM + r0 + j0] = o;
    }
}

__global__ __launch_bounds__(256)
void transpose_fast(const float* __restrict__ src, u16* __restrict__ dst)
{
    transpose_body(src, dst, blockIdx.x, blockIdx.y, threadIdx.x);
}

// fused prep: z=0 cvt x->bf16, z=1..3 W^T
__global__ __launch_bounds__(256)
void prep4(const float* __restrict__ x,
           const float* __restrict__ Wq, const float* __restrict__ Wk,
           const float* __restrict__ Wv,
           u16* __restrict__ XB, u16* T0, u16* T1, u16* T2)
{
    const int z = blockIdx.z, t = threadIdx.x, bx = blockIdx.x;
    if (z == 0) {
        long i0 = ((long)bx * 256 + t) * 16;
        short8 o0, o1;
#pragma unroll
        for (int j = 0; j < 2; ++j) {
            float4 a = *(const float4*)&x[i0 + j * 8];
            float4 b = *(const float4*)&x[i0 + j * 8 + 4];
            short8& o = j ? o1 : o0;
            o[0] = (short)f2bf(a.x); o[1] = (short)f2bf(a.y);
            o[2] = (short)f2bf(a.z); o[3] = (short)f2bf(a.w);
            o[4] = (short)f2bf(b.x); o[5] = (short)f2bf(b.y);
            o[6] = (short)f2bf(b.z); o[7] = (short)f2bf(b.w);
        }
        *(short8*)&XB[i0] = o0;
        *(short8*)&XB[i0 + 8] = o1;
    } else {
        const float* src = (z == 1) ? Wq : (z == 2) ? Wk : Wv;
        u16* dst         = (z == 1) ? T0 : (z == 2) ? T1 : T2;
        transpose_body(src, dst, bx & 31, bx >> 5, t);
    }
}

__global__ __launch_bounds__(256)
void cvt_bf16(const float* __restrict__ src, u16* __restrict__ dst)
{
    int i = (blockIdx.x * 256 + threadIdx.x) * 4;
    float4 v = *(const float4*)(src + i);
    ushort4 o;
    o.x = f2bf(v.x); o.y = f2bf(v.y); o.z = f2bf(v.z); o.w = f2bf(v.w);
    *(ushort4*)(dst + i) = o;
}

// ---------------------------------------------------------------------------
// 128x128-tile GEMM, m97-style global_load_lds staging. z0 -> Q (scaled
// 1/8*log2e), z1 -> K, z2 -> V^T via operand-swapped MFMA (contig stores).
// ---------------------------------------------------------------------------
__global__ __launch_bounds__(256, 2)
void gemm128(const u16* __restrict__ A,
             const u16* B0, const u16* B1, const u16* B2,
             u16* C0, u16* C1, u16* C2, int zbase)
{
    const int Kd = D_DIM, N = D_DIM, M = S_DIM;
    const int z = blockIdx.z + zbase;
    const u16* Bt = (z == 0) ? B0 : (z == 1) ? B1 : B2;
    u16* C        = (z == 0) ? C0 : (z == 1) ? C1 : C2;

    __shared__ __attribute__((aligned(16))) u16 As[128 * 32];
    __shared__ __attribute__((aligned(16))) u16 Bs[128 * 32];

    const int tid = threadIdx.x, lane = tid & 63, wave = tid >> 6;
    const int bm = blockIdx.x * 128, bn = blockIdx.y * 128;

    const int lrow = lane >> 2;
    const int gchunk = (lane & 3) ^ ((lane >> 3) & 3);
    const long aoff0 = (long)(bm + wave * 32 + lrow) * Kd + gchunk * 8;
    const long aoff1 = aoff0 + 16L * Kd;
    const long boff0 = (long)(bn + wave * 32 + lrow) * Kd + gchunk * 8;
    const long boff1 = boff0 + 16L * Kd;
    u16* as0 = &As[wave * 1024];
    u16* as1 = &As[wave * 1024 + 512];
    u16* bs0 = &Bs[wave * 1024];
    u16* bs1 = &Bs[wave * 1024 + 512];

    const int wr = (wave >> 1) * 64, wc = (wave & 1) * 64;
    const int fr = lane & 15, fq = lane >> 4;

    f32x4 acc[4][4];
    for (int i = 0; i < 4; ++i)
        for (int j = 0; j < 4; ++j) { f32x4 zz = {0.f,0.f,0.f,0.f}; acc[i][j] = zz; }

    for (int k0 = 0; k0 < Kd; k0 += 32) {
        gload16(A + aoff0 + k0, as0);
        gload16(A + aoff1 + k0, as1);
        gload16(Bt + boff0 + k0, bs0);
        gload16(Bt + boff1 + k0, bs1);
        __syncthreads();

        short8 af[4], bf[4];
#pragma unroll
        for (int i = 0; i < 4; ++i) {
            int m = wr + i * 16 + fr;
            int slot = fq ^ ((m >> 1) & 3);
            af[i] = *(const short8*)&As[m * 32 + slot * 8];
            int n = wc + i * 16 + fr;
            int slotb = fq ^ ((n >> 1) & 3);
            bf[i] = *(const short8*)&Bs[n * 32 + slotb * 8];
        }
        if (z == 2) {
#pragma unroll
            for (int i = 0; i < 4; ++i)
#pragma unroll
                for (int j = 0; j < 4; ++j)
                    acc[i][j] = __builtin_amdgcn_mfma_f32_16x16x32_bf16(bf[j], af[i], acc[i][j], 0, 0, 0);
        } else {
#pragma unroll
            for (int i = 0; i < 4; ++i)
#pragma unroll
                for (int j = 0; j < 4; ++j)
                    acc[i][j] = __builtin_amdgcn_mfma_f32_16x16x32_bf16(af[i], bf[j], acc[i][j], 0, 0, 0);
        }
        __syncthreads();
    }

    if (z == 2) {
#pragma unroll
        for (int i = 0; i < 4; ++i) {
            int tok = bm + wr + i * 16 + fr;
#pragma unroll
            for (int j = 0; j < 4; ++j) {
                int ch = bn + wc + j * 16 + fq * 4;
#pragma unroll
                for (int r = 0; r < 4; ++r)
                    C[(long)(ch + r) * M + tok] = f2bf(acc[i][j][r]);
            }
        }
    } else {
        const float sc = (z == 0) ? 0.125f * 1.44269504f : 1.0f;  // Q log2-domain
#pragma unroll
        for (int i = 0; i < 4; ++i) {
            int row = bm + wr + i * 16 + fq * 4;
#pragma unroll
            for (int j = 0; j < 4; ++j) {
                int col = bn + wc + j * 16 + fr;
#pragma unroll
                for (int r = 0; r < 4; ++r)
                    C[(long)(row + r) * N + col] = f2bf(acc[i][j][r] * sc);
            }
        }
    }
}

// ---------------------------------------------------------------------------
// 64x128-tile GEMM, fp32 output, m97-style global_load_lds staging.
// ---------------------------------------------------------------------------
__global__ __launch_bounds__(256, 2)
void gemm_out(const u16* __restrict__ A, const u16* __restrict__ Bt,
              float* __restrict__ C)
{
    const int Kd = D_DIM, N = D_DIM;

    __shared__ __attribute__((aligned(16))) u16 As[64 * 32];
    __shared__ __attribute__((aligned(16))) u16 Bs[128 * 32];

    const int tid = threadIdx.x, lane = tid & 63, wave = tid >> 6;
    const int bm = blockIdx.x * 64, bn = blockIdx.y * 128;

    const int lrow = lane >> 2;
    const int gchunk = (lane & 3) ^ ((lane >> 3) & 3);
    const long aoff  = (long)(bm + wave * 16 + lrow) * Kd + gchunk * 8;
    const long boff0 = (long)(bn + wave * 32 + lrow) * Kd + gchunk * 8;
    const long boff1 = boff0 + 16L * Kd;
    u16* as  = &As[wave * 512];
    u16* bs0 = &Bs[wave * 1024];
    u16* bs1 = &Bs[wave * 1024 + 512];

    const int wr = (wave >> 1) * 32, wc = (wave & 1) * 64;
    const int fr = lane & 15, fq = lane >> 4;

    f32x4 acc[2][4];
    for (int i = 0; i < 2; ++i)
        for (int j = 0; j < 4; ++j) { f32x4 zz = {0.f,0.f,0.f,0.f}; acc[i][j] = zz; }

    for (int k0 = 0; k0 < Kd; k0 += 32) {
        gload16(A + aoff + k0, as);
        gload16(Bt + boff0 + k0, bs0);
        gload16(Bt + boff1 + k0, bs1);
        __syncthreads();

        short8 af[2], bf[4];
#pragma unroll
        for (int i = 0; i < 2; ++i) {
            int m = wr + i * 16 + fr;
            int slot = fq ^ ((m >> 1) & 3);
            af[i] = *(const short8*)&As[m * 32 + slot * 8];
        }
#pragma unroll
        for (int j = 0; j < 4; ++j) {
            int n = wc + j * 16 + fr;
            int slotb = fq ^ ((n >> 1) & 3);
            bf[j] = *(const short8*)&Bs[n * 32 + slotb * 8];
        }
#pragma unroll
        for (int i = 0; i < 2; ++i)
#pragma unroll
            for (int j = 0; j < 4; ++j)
                acc[i][j] = __builtin_amdgcn_mfma_f32_16x16x32_bf16(af[i], bf[j], acc[i][j], 0, 0, 0);
        __syncthreads();
    }

#pragma unroll
    for (int i = 0; i < 2; ++i) {
        int row = bm + wr + i * 16 + fq * 4;
#pragma unroll
        for (int j = 0; j < 4; ++j) {
            int col = bn + wc + j * 16 + fr;
#pragma unroll
            for (int r = 0; r < 4; ++r)
                C[(long)(row + r) * N + col] = acc[i][j][r];
        }
    }
}

// ---------------------------------------------------------------------------
// Differential flash attention + fused GroupNorm — 32 QUERIES PER WAVE.
// r9 counters: LDS-read bound (each wave reads full K+V tile per kb). Now
// each wave owns 2 m-tiles; K/V fragments are read ONCE and feed 4 MFMAs
// (2 m-tiles x 2 streams) -> LDS bytes per FLOP halved. Staging via
// global_load_lds + dbuf (no padding; XOR chunk swizzle (lane&7)^(row&7),
// which is 2-way/free and a per-lane constant since row strides are mult-16).
// launch_bounds(256,1): 512-VGPR budget, no spill (r4's failure was a
// 128-VGPR cap). Grid (16,16) = 256 blocks = 1/CU; LDS 64 KB/block.
// ---------------------------------------------------------------------------
__global__ __launch_bounds__(256, 1)
void diff_attn(const u16* __restrict__ Qm, const u16* __restrict__ Km,
               const u16* __restrict__ Vt,
               const float* __restrict__ lq1, const float* __restrict__ lk1,
               const float* __restrict__ lq2, const float* __restrict__ lk2,
               const float* __restrict__ gw, const float* __restrict__ gb,
               u16* __restrict__ Y)
{
    __shared__ __attribute__((aligned(16))) u16 K1s[2][64 * 64];
    __shared__ __attribute__((aligned(16))) u16 K2s[2][64 * 64];
    __shared__ __attribute__((aligned(16))) u16 Vts[2][128 * 64];

    const int tid = threadIdx.x, lane = tid & 63, wave = tid >> 6;
    const int h = blockIdx.y;
    const int q0 = blockIdx.x * 128 + wave * 32;
    const int fr = lane & 15, qq = lane >> 4;

    float d1 = 0.f, d2 = 0.f;
    for (int i = 0; i < DH_NUM; ++i) {
        d1 += lq1[i] * lk1[i];
        d2 += lq2[i] * lk2[i];
    }
    const float lam = __expf(d1) - __expf(d2) + 0.8f;

    // Q fragments (S^T B-operand: n = fr = query, k = qq*8 + j), per m-tile
    short8 q1f[2][2], q2f[2][2];
#pragma unroll
    for (int mt = 0; mt < 2; ++mt) {
        const u16* qb = Qm + (long)(q0 + mt * 16 + fr) * D_DIM + h * 128;
        q1f[mt][0] = *(const short8*)(qb + qq * 8);
        q1f[mt][1] = *(const short8*)(qb + 32 + qq * 8);
        q2f[mt][0] = *(const short8*)(qb + 64 + qq * 8);
        q2f[mt][1] = *(const short8*)(qb + 96 + qq * 8);
    }

    // O^T accumulators: channel = n*16 + qq*4 + r, query = fr (per m-tile)
    f32x4 a1[2][8], a2[2][8];
    for (int mt = 0; mt < 2; ++mt)
        for (int n = 0; n < 8; ++n) { f32x4 zz = {0.f,0.f,0.f,0.f}; a1[mt][n] = zz; a2[mt][n] = zz; }
    float ls1[2] = {0.f, 0.f}, ls2[2] = {0.f, 0.f};

    // staging constants: lane covers row base+ (lane>>3), chunk (lane&7)^(lane>>3)
    const int grow = lane >> 3;
    const int gcol = ((lane & 7) ^ grow) * 8;

    auto fill = [&](int kb, int b) {
        const long krow = (long)(kb * 64) * D_DIM + h * 128;
#pragma unroll
        for (int g = 0; g < 2; ++g) {
            int t = wave * 16 + g * 8 + grow;
            gload16(Km + krow + (long)t * D_DIM + gcol,
                    &K1s[b][(wave * 16 + g * 8) * 64]);
            gload16(Km + krow + (long)t * D_DIM + 64 + gcol,
                    &K2s[b][(wave * 16 + g * 8) * 64]);
        }
#pragma unroll
        for (int g = 0; g < 4; ++g) {
            int ch = wave * 32 + g * 8 + grow;
            gload16(Vt + (long)(h * 128 + ch) * S_DIM + kb * 64 + gcol,
                    &Vts[b][(wave * 32 + g * 8) * 64]);
        }
    };

    // read-side swizzle (row&7 == fr&7 because row strides are multiples of 16)
    const int swz = fr & 7;
    const int kc0 = ((qq ^ swz) * 8);               // ks=0 chunk
    const int kc1 = (((4 + qq) ^ swz) * 8);         // ks=1 chunk
    int vo[4];
#pragma unroll
    for (int j = 0; j < 4; ++j)
        vo[j] = (((j * 2 + (qq >> 1)) ^ swz) * 8) + (qq & 1) * 4;

    fill(0, 0);
    int p = 0;

    for (int kb = 0; kb < S_DIM / 64; ++kb) {
        __syncthreads();   // buf p fills drained (vmcnt before barrier); p^1 reads done
        if (kb + 1 < S_DIM / 64) fill(kb + 1, p ^ 1);

#pragma unroll
        for (int j = 0; j < 4; ++j) {   // key tile: t = j*16 + qq*4 + r
            const int rowK = (j * 16 + fr) * 64;
            f32x4 s1[2], s2[2];
            { f32x4 zz = {0.f,0.f,0.f,0.f}; s1[0]=zz; s1[1]=zz; s2[0]=zz; s2[1]=zz; }
            {
                short8 k1 = *(const short8*)&K1s[p][rowK + kc0];
                short8 k2 = *(const short8*)&K2s[p][rowK + kc0];
#pragma unroll
                for (int mt = 0; mt < 2; ++mt) {
                    s1[mt] = __builtin_amdgcn_mfma_f32_16x16x32_bf16(k1, q1f[mt][0], s1[mt], 0, 0, 0);
                    s2[mt] = __builtin_amdgcn_mfma_f32_16x16x32_bf16(k2, q2f[mt][0], s2[mt], 0, 0, 0);
                }
            }
            {
                short8 k1 = *(const short8*)&K1s[p][rowK + kc1];
                short8 k2 = *(const short8*)&K2s[p][rowK + kc1];
#pragma unroll
                for (int mt = 0; mt < 2; ++mt) {
                    s1[mt] = __builtin_amdgcn_mfma_f32_16x16x32_bf16(k1, q1f[mt][1], s1[mt], 0, 0, 0);
                    s2[mt] = __builtin_amdgcn_mfma_f32_16x16x32_bf16(k2, q2f[mt][1], s2[mt], 0, 0, 0);
                }
            }
            union { short4v s; unsigned u[2]; } P1[2], P2[2];
#pragma unroll
            for (int mt = 0; mt < 2; ++mt) {
                float e1[4], e2[4];
#pragma unroll
                for (int r = 0; r < 4; ++r) {
                    e1[r] = EXP2(s1[mt][r]);        // Q pre-scaled by log2e
                    e2[r] = EXP2(s2[mt][r]);
                    ls1[mt] += e1[r]; ls2[mt] += e2[r];
                }
                P1[mt].u[0] = pk_bf16(e1[0], e1[1]); P1[mt].u[1] = pk_bf16(e1[2], e1[3]);
                P2[mt].u[0] = pk_bf16(e2[0], e2[1]); P2[mt].u[1] = pk_bf16(e2[2], e2[3]);
            }
            // PV: O^T += V^T * P^T — vf read once, feeds 4 MFMAs
#pragma unroll
            for (int n = 0; n < 8; ++n) {
                short4v vf = *(const short4v*)&Vts[p][(n * 16 + fr) * 64 + vo[j]];
#pragma unroll
                for (int mt = 0; mt < 2; ++mt) {
                    a1[mt][n] = __builtin_amdgcn_mfma_f32_16x16x16bf16_1k(vf, P1[mt].s, a1[mt][n], 0, 0, 0);
                    a2[mt][n] = __builtin_amdgcn_mfma_f32_16x16x16bf16_1k(vf, P2[mt].s, a2[mt][n], 0, 0, 0);
                }
            }
        }
        p ^= 1;
    }

    // ---- epilogue per m-tile (sequential to cap live registers)
#pragma unroll
    for (int mt = 0; mt < 2; ++mt) {
        float L1 = ls1[mt], L2 = ls2[mt];
        L1 += __shfl_xor(L1, 16, 64); L1 += __shfl_xor(L1, 32, 64);
        L2 += __shfl_xor(L2, 16, 64); L2 += __shfl_xor(L2, 32, 64);
        const float i1 = 1.f / L1, i2 = lam / L2;

        float o[8][4], sum = 0.f, sq = 0.f;
#pragma unroll
        for (int n = 0; n < 8; ++n)
#pragma unroll
            for (int r = 0; r < 4; ++r) {
                float v = a1[mt][n][r] * i1 - a2[mt][n][r] * i2;
                o[n][r] = v; sum += v; sq += v * v;
            }
        sum += __shfl_xor(sum, 16, 64); sum += __shfl_xor(sum, 32, 64);
        sq  += __shfl_xor(sq, 16, 64);  sq  += __shfl_xor(sq, 32, 64);
        const float mean = sum * (1.f / 128.f);
        const float var = sq * (1.f / 128.f) - mean * mean;
        const float inv = rsqrtf(var + 1e-5f);

        const long yrow = (long)(q0 + mt * 16 + fr) * D_DIM + h * 128;
#pragma unroll
        for (int n = 0; n < 8; ++n) {
            float4 g4 = *(const float4*)&gw[h * 128 + n * 16 + qq * 4];
            float4 b4 = *(const float4*)&gb[h * 128 + n * 16 + qq * 4];
            ushort4 st;
            st.x = f2bf(((o[n][0] - mean) * inv * g4.x + b4.x) * 0.2f);
            st.y = f2bf(((o[n][1] - mean) * inv * g4.y + b4.y) * 0.2f);
            st.z = f2bf(((o[n][2] - mean) * inv * g4.z + b4.z) * 0.2f);
            st.w = f2bf(((o[n][3] - mean) * inv * g4.w + b4.w) * 0.2f);
            *(ushort4*)&Y[yrow + n * 16 + qq * 4] = st;
        }
    }
}

// ---------------------------------------------------------------------------
extern "C" void kernel_launch(void* const* d_in, const int* in_sizes, int n_in,
                              void* d_out, int out_size, void* d_ws, size_t ws_size,
                              hipStream_t stream)
{
    const float* x   = (const float*)d_in[0];
    const float* Wq  = (const float*)d_in[1];
    const float* Wk  = (const float*)d_in[2];
    const float* Wv  = (const float*)d_in[3];
    const float* Wo  = (const float*)d_in[4];
    const float* lq1 = (const float*)d_in[5];
    const float* lk1 = (const float*)d_in[6];
    const float* lq2 = (const float*)d_in[7];
    const float* lk2 = (const float*)d_in[8];
    const float* gw  = (const float*)d_in[9];
    const float* gb  = (const float*)d_in[10];

    char* ws = (char*)d_ws;
    const size_t SEG = (size_t)D_DIM * D_DIM * sizeof(u16);   // 8 MiB
    const dim3 tgrid(32, 32), agrid(16, 16), ogrid(32, 16);

    if (ws_size >= 7 * SEG) {
        u16* XB  = (u16*)(ws + 0 * SEG);
        u16* WTq = (u16*)(ws + 1 * SEG);
        u16* WTk = (u16*)(ws + 2 * SEG);
        u16* WTv = (u16*)(ws + 3 * SEG);
        u16* Qb  = (u16*)(ws + 4 * SEG);
        u16* Kb  = (u16*)(ws + 5 * SEG);
        u16* Vt  = (u16*)(ws + 6 * SEG);
        u16* WTo = WTq;   // dead after QKV GEMM
        u16* Yb  = WTk;   // dead after QKV GEMM

        prep4<<<dim3(1024, 1, 4), 256, 0, stream>>>(x, Wq, Wk, Wv,
                                                    XB, WTq, WTk, WTv);
        gemm128<<<dim3(16, 16, 3), 256, 0, stream>>>(XB, WTq, WTk, WTv,
                                                     Qb, Kb, Vt, 0);
        transpose_fast<<<tgrid, 256, 0, stream>>>(Wo, WTo);
        diff_attn<<<agrid, 256, 0, stream>>>(Qb, Kb, Vt, lq1, lk1, lq2, lk2,
                                             gw, gb, Yb);
        gemm_out<<<ogrid, 256, 0, stream>>>(Yb, WTo, (float*)d_out);
    } else {
        u16* XB = (u16*)(ws + 0 * SEG);
        u16* WT = (u16*)(ws + 1 * SEG);
        u16* Qb = (u16*)(ws + 2 * SEG);
        u16* Kb = (u16*)(ws + 3 * SEG);
        u16* Vt = (u16*)(ws + 4 * SEG);

        cvt_bf16<<<4096, 256, 0, stream>>>(x, XB);
        transpose_fast<<<tgrid, 256, 0, stream>>>(Wq, WT);
        gemm128<<<dim3(16, 16, 1), 256, 0, stream>>>(XB, WT, WT, WT, Qb, Qb, Qb, 0);
        transpose_fast<<<tgrid, 256, 0, stream>>>(Wk, WT);
        gemm128<<<dim3(16, 16, 1), 256, 0, stream>>>(XB, WT, WT, WT, Kb, Kb, Kb, 1);
        transpose_fast<<<tgrid, 256, 0, stream>>>(Wv, WT);
        gemm128<<<dim3(16, 16, 1), 256, 0, stream>>>(XB, WT, WT, WT, Vt, Vt, Vt, 2);
        diff_attn<<<agrid, 256, 0, stream>>>(Qb, Kb, Vt, lq1, lk1, lq2, lk2,
                                             gw, gb, XB);
        transpose_fast<<<tgrid, 256, 0, stream>>>(Wo, WT);
        gemm_out<<<ogrid, 256, 0, stream>>>(XB, WT, (float*)d_out);
    }
}

// Round 11
// 308.339 us; speedup vs baseline: 1.1305x; 1.1305x over previous
//
#include <hip/hip_runtime.h>
#include <hip/hip_bf16.h>

typedef unsigned short u16;
typedef __attribute__((ext_vector_type(8))) short short8;   // 8 x bf16 bits
typedef __attribute__((ext_vector_type(4))) short short4v;  // 4 x bf16 bits
typedef __attribute__((ext_vector_type(4))) float f32x4;

#define S_DIM 2048
#define D_DIM 2048
#define H_NUM 16
#define DH_NUM 64

#if __has_builtin(__builtin_amdgcn_exp2f)
#define EXP2(x) __builtin_amdgcn_exp2f(x)
#else
#define EXP2(x) exp2f(x)
#endif

__device__ __forceinline__ u16 f2bf(float f) {
    union { float f; unsigned u; } x; x.f = f;
    unsigned r = x.u + 0x7fff + ((x.u >> 16) & 1);   // RNE
    return (u16)(r >> 16);
}

// pack 2 fp32 -> 2 bf16 (RNE) in one v_cvt_pk_bf16_f32
__device__ __forceinline__ unsigned pk_bf16(float a, float b) {
    union { __hip_bfloat162 h; unsigned u; } cv;
    float2 t; t.x = a; t.y = b;
    cv.h = __float22bfloat162_rn(t);
    return cv.u;
}

// async global->LDS, 16B per lane; LDS dest = wave-uniform base + lane*16
__device__ __forceinline__ void gload16(const void* g, void* l) {
    __builtin_amdgcn_global_load_lds(
        (const __attribute__((address_space(1))) unsigned int*)g,
        (__attribute__((address_space(3))) unsigned int*)l, 16, 0, 0);
}

// ---------------------------------------------------------------------------
// Fast transpose body: 64x64 fp32 LDS tile, float4 reads, 16B bf16 stores.
// ---------------------------------------------------------------------------
__device__ __forceinline__ void transpose_body(const float* __restrict__ src,
                                               u16* __restrict__ dst,
                                               int tx, int ty, int t)
{
    __shared__ float tile[64][65];
    const int r0 = ty * 64, c0 = tx * 64;
#pragma unroll
    for (int p = 0; p < 4; ++p) {
        int r = p * 16 + (t >> 4), c = (t & 15) * 4;
        float4 v = *(const float4*)&src[(long)(r0 + r) * D_DIM + c0 + c];
        tile[r][c] = v.x; tile[r][c + 1] = v.y;
        tile[r][c + 2] = v.z; tile[r][c + 3] = v.w;
    }
    __syncthreads();
#pragma unroll
    for (int p = 0; p < 2; ++p) {
        int ch = t + p * 256;
        int i = ch >> 3, j0 = (ch & 7) * 8;
        short8 o;
#pragma unroll
        for (int jj = 0; jj < 8; ++jj)
            o[jj] = (short)f2bf(tile[j0 + jj][i]);
        *(short8*)&dst[(long)(c0 + i) * D_DIM + r0 + j0] = o;
    }
}

__global__ __launch_bounds__(256)
void transpose_fast(const float* __restrict__ src, u16* __restrict__ dst)
{
    transpose_body(src, dst, blockIdx.x, blockIdx.y, threadIdx.x);
}

// fused prep: z=0 cvt x->bf16, z=1..3 W^T
__global__ __launch_bounds__(256)
void prep4(const float* __restrict__ x,
           const float* __restrict__ Wq, const float* __restrict__ Wk,
           const float* __restrict__ Wv,
           u16* __restrict__ XB, u16* T0, u16* T1, u16* T2)
{
    const int z = blockIdx.z, t = threadIdx.x, bx = blockIdx.x;
    if (z == 0) {
        long i0 = ((long)bx * 256 + t) * 16;
        short8 o0, o1;
#pragma unroll
        for (int j = 0; j < 2; ++j) {
            float4 a = *(const float4*)&x[i0 + j * 8];
            float4 b = *(const float4*)&x[i0 + j * 8 + 4];
            short8& o = j ? o1 : o0;
            o[0] = (short)f2bf(a.x); o[1] = (short)f2bf(a.y);
            o[2] = (short)f2bf(a.z); o[3] = (short)f2bf(a.w);
            o[4] = (short)f2bf(b.x); o[5] = (short)f2bf(b.y);
            o[6] = (short)f2bf(b.z); o[7] = (short)f2bf(b.w);
        }
        *(short8*)&XB[i0] = o0;
        *(short8*)&XB[i0 + 8] = o1;
    } else {
        const float* src = (z == 1) ? Wq : (z == 2) ? Wk : Wv;
        u16* dst         = (z == 1) ? T0 : (z == 2) ? T1 : T2;
        transpose_body(src, dst, bx & 31, bx >> 5, t);
    }
}

__global__ __launch_bounds__(256)
void cvt_bf16(const float* __restrict__ src, u16* __restrict__ dst)
{
    int i = (blockIdx.x * 256 + threadIdx.x) * 4;
    float4 v = *(const float4*)(src + i);
    ushort4 o;
    o.x = f2bf(v.x); o.y = f2bf(v.y); o.z = f2bf(v.z); o.w = f2bf(v.w);
    *(ushort4*)(dst + i) = o;
}

// ---------------------------------------------------------------------------
// 128x128-tile GEMM, BK=64 (32 K-iters — half the barrier drains of BK=32),
// global_load_lds staging with r10-proven XOR-chunk swizzle:
// LDS slot s of row r holds global chunk s^(r&7); rows are 128B (64 u16) so
// bank = slot only -> b128 reads are 2-way (free). z0 -> Q (scaled
// 1/8*log2e), z1 -> K, z2 -> V^T via operand-swapped MFMA (contig stores).
// LDS 2x16 KB = 32 KB -> still 2 blocks/CU.
// ---------------------------------------------------------------------------
__global__ __launch_bounds__(256, 2)
void gemm128(const u16* __restrict__ A,
             const u16* B0, const u16* B1, const u16* B2,
             u16* C0, u16* C1, u16* C2, int zbase)
{
    const int Kd = D_DIM, N = D_DIM, M = S_DIM;
    const int z = blockIdx.z + zbase;
    const u16* Bt = (z == 0) ? B0 : (z == 1) ? B1 : B2;
    u16* C        = (z == 0) ? C0 : (z == 1) ? C1 : C2;

    __shared__ __attribute__((aligned(16))) u16 As[128 * 64];
    __shared__ __attribute__((aligned(16))) u16 Bs[128 * 64];

    const int tid = threadIdx.x, lane = tid & 63, wave = tid >> 6;
    const int bm = blockIdx.x * 128, bn = blockIdx.y * 128;

    // staging: wave covers rows wave*32..+31 (4 groups of 8 rows);
    // lane -> row group+ (lane>>3), global chunk ((lane&7)^(lane>>3))
    const int grow = lane >> 3;
    const int gcol = ((lane & 7) ^ grow) * 8;

    const int wr = (wave >> 1) * 64, wc = (wave & 1) * 64;
    const int fr = lane & 15, fq = lane >> 4;
    const int swz = fr & 7;

    f32x4 acc[4][4];
    for (int i = 0; i < 4; ++i)
        for (int j = 0; j < 4; ++j) { f32x4 zz = {0.f,0.f,0.f,0.f}; acc[i][j] = zz; }

    for (int k0 = 0; k0 < Kd; k0 += 64) {
#pragma unroll
        for (int g = 0; g < 4; ++g) {
            int r = wave * 32 + g * 8;
            gload16(A + (long)(bm + r + grow) * Kd + k0 + gcol, &As[r * 64]);
            gload16(Bt + (long)(bn + r + grow) * Kd + k0 + gcol, &Bs[r * 64]);
        }
        __syncthreads();

#pragma unroll
        for (int ks = 0; ks < 2; ++ks) {
            const int slot = ((fq + ks * 4) ^ swz) * 8;
            short8 af[4], bf[4];
#pragma unroll
            for (int i = 0; i < 4; ++i) {
                af[i] = *(const short8*)&As[(wr + i * 16 + fr) * 64 + slot];
                bf[i] = *(const short8*)&Bs[(wc + i * 16 + fr) * 64 + slot];
            }
            if (z == 2) {
#pragma unroll
                for (int i = 0; i < 4; ++i)
#pragma unroll
                    for (int j = 0; j < 4; ++j)
                        acc[i][j] = __builtin_amdgcn_mfma_f32_16x16x32_bf16(bf[j], af[i], acc[i][j], 0, 0, 0);
            } else {
#pragma unroll
                for (int i = 0; i < 4; ++i)
#pragma unroll
                    for (int j = 0; j < 4; ++j)
                        acc[i][j] = __builtin_amdgcn_mfma_f32_16x16x32_bf16(af[i], bf[j], acc[i][j], 0, 0, 0);
            }
        }
        __syncthreads();
    }

    if (z == 2) {
        // swapped layout: row (fq*4+r) = channel, col (fr) = token -> contig
#pragma unroll
        for (int i = 0; i < 4; ++i) {
            int tok = bm + wr + i * 16 + fr;
#pragma unroll
            for (int j = 0; j < 4; ++j) {
                int ch = bn + wc + j * 16 + fq * 4;
#pragma unroll
                for (int r = 0; r < 4; ++r)
                    C[(long)(ch + r) * M + tok] = f2bf(acc[i][j][r]);
            }
        }
    } else {
        const float sc = (z == 0) ? 0.125f * 1.44269504f : 1.0f;  // Q log2-domain
#pragma unroll
        for (int i = 0; i < 4; ++i) {
            int row = bm + wr + i * 16 + fq * 4;
#pragma unroll
            for (int j = 0; j < 4; ++j) {
                int col = bn + wc + j * 16 + fr;
#pragma unroll
                for (int r = 0; r < 4; ++r)
                    C[(long)(row + r) * N + col] = f2bf(acc[i][j][r] * sc);
            }
        }
    }
}

// ---------------------------------------------------------------------------
// 64x128-tile GEMM, fp32 output, BK=64, same staging scheme. LDS 24 KB.
// ---------------------------------------------------------------------------
__global__ __launch_bounds__(256, 2)
void gemm_out(const u16* __restrict__ A, const u16* __restrict__ Bt,
              float* __restrict__ C)
{
    const int Kd = D_DIM, N = D_DIM;

    __shared__ __attribute__((aligned(16))) u16 As[64 * 64];
    __shared__ __attribute__((aligned(16))) u16 Bs[128 * 64];

    const int tid = threadIdx.x, lane = tid & 63, wave = tid >> 6;
    const int bm = blockIdx.x * 64, bn = blockIdx.y * 128;

    const int grow = lane >> 3;
    const int gcol = ((lane & 7) ^ grow) * 8;

    const int wr = (wave >> 1) * 32, wc = (wave & 1) * 64;
    const int fr = lane & 15, fq = lane >> 4;
    const int swz = fr & 7;

    f32x4 acc[2][4];
    for (int i = 0; i < 2; ++i)
        for (int j = 0; j < 4; ++j) { f32x4 zz = {0.f,0.f,0.f,0.f}; acc[i][j] = zz; }

    for (int k0 = 0; k0 < Kd; k0 += 64) {
#pragma unroll
        for (int g = 0; g < 2; ++g) {
            int r = wave * 16 + g * 8;
            gload16(A + (long)(bm + r + grow) * Kd + k0 + gcol, &As[r * 64]);
        }
#pragma unroll
        for (int g = 0; g < 4; ++g) {
            int r = wave * 32 + g * 8;
            gload16(Bt + (long)(bn + r + grow) * Kd + k0 + gcol, &Bs[r * 64]);
        }
        __syncthreads();

#pragma unroll
        for (int ks = 0; ks < 2; ++ks) {
            const int slot = ((fq + ks * 4) ^ swz) * 8;
            short8 af[2], bf[4];
#pragma unroll
            for (int i = 0; i < 2; ++i)
                af[i] = *(const short8*)&As[(wr + i * 16 + fr) * 64 + slot];
#pragma unroll
            for (int j = 0; j < 4; ++j)
                bf[j] = *(const short8*)&Bs[(wc + j * 16 + fr) * 64 + slot];
#pragma unroll
            for (int i = 0; i < 2; ++i)
#pragma unroll
                for (int j = 0; j < 4; ++j)
                    acc[i][j] = __builtin_amdgcn_mfma_f32_16x16x32_bf16(af[i], bf[j], acc[i][j], 0, 0, 0);
        }
        __syncthreads();
    }

#pragma unroll
    for (int i = 0; i < 2; ++i) {
        int row = bm + wr + i * 16 + fq * 4;
#pragma unroll
        for (int j = 0; j < 4; ++j) {
            int col = bn + wc + j * 16 + fr;
#pragma unroll
            for (int r = 0; r < 4; ++r)
                C[(long)(row + r) * N + col] = acc[i][j][r];
        }
    }
}

// ---------------------------------------------------------------------------
// Differential flash attention + fused GroupNorm — r9-PROVEN version (92.6 µs,
// 2 blocks/CU). r10's 32q/wave halved LDS traffic but dropped occupancy to
// 1 block/CU (4 waves) and lost 21 µs to latency exposure — reverted.
// dbuf K/V LDS (register-staged), S^T=K*Q^T chains in-register into
// O^T=V^T*P^T, exp2-domain softmax, packed bf16 cvt, GN fused in epilogue.
// ---------------------------------------------------------------------------
__global__ __launch_bounds__(256, 2)
void diff_attn(const u16* __restrict__ Qm, const u16* __restrict__ Km,
               const u16* __restrict__ Vt,
               const float* __restrict__ lq1, const float* __restrict__ lk1,
               const float* __restrict__ lq2, const float* __restrict__ lk2,
               const float* __restrict__ gw, const float* __restrict__ gb,
               u16* __restrict__ Y)
{
    __shared__ __attribute__((aligned(16))) u16 K1s[2][64 * 72];
    __shared__ __attribute__((aligned(16))) u16 K2s[2][64 * 72];
    __shared__ __attribute__((aligned(16))) u16 Vts[2][128 * 72];

    const int tid = threadIdx.x, lane = tid & 63, wave = tid >> 6;
    const int h = blockIdx.y;
    const int q0 = blockIdx.x * 64 + wave * 16;
    const int fr = lane & 15, qq = lane >> 4;

    float d1 = 0.f, d2 = 0.f;
    for (int i = 0; i < DH_NUM; ++i) {
        d1 += lq1[i] * lk1[i];
        d2 += lq2[i] * lk2[i];
    }
    const float lam = __expf(d1) - __expf(d2) + 0.8f;

    short8 q1f[2], q2f[2];
    {
        const u16* qb = Qm + (long)(q0 + fr) * D_DIM + h * 128;
        q1f[0] = *(const short8*)(qb + qq * 8);
        q1f[1] = *(const short8*)(qb + 32 + qq * 8);
        q2f[0] = *(const short8*)(qb + 64 + qq * 8);
        q2f[1] = *(const short8*)(qb + 96 + qq * 8);
    }

    f32x4 a1[8], a2[8];
    for (int n = 0; n < 8; ++n) { f32x4 zz = {0.f,0.f,0.f,0.f}; a1[n] = zz; a2[n] = zz; }
    float ls1 = 0.f, ls2 = 0.f;

    const int t0 = tid >> 3, c0 = tid & 7;
    short8 k1r[2], k2r[2], vr[4];

    auto load_tile = [&](int kb) {
        const long krow = (long)(kb * 64) * D_DIM + h * 128;
        k1r[0] = *(const short8*)&Km[krow + (long)t0 * D_DIM + c0 * 8];
        k2r[0] = *(const short8*)&Km[krow + (long)t0 * D_DIM + 64 + c0 * 8];
        k1r[1] = *(const short8*)&Km[krow + (long)(t0 + 32) * D_DIM + c0 * 8];
        k2r[1] = *(const short8*)&Km[krow + (long)(t0 + 32) * D_DIM + 64 + c0 * 8];
#pragma unroll
        for (int it = 0; it < 4; ++it)
            vr[it] = *(const short8*)&Vt[(long)(h * 128 + t0 + it * 32) * S_DIM + kb * 64 + c0 * 8];
    };
    auto store_tile = [&](int b) {
        *(short8*)&K1s[b][t0 * 72 + c0 * 8] = k1r[0];
        *(short8*)&K2s[b][t0 * 72 + c0 * 8] = k2r[0];
        *(short8*)&K1s[b][(t0 + 32) * 72 + c0 * 8] = k1r[1];
        *(short8*)&K2s[b][(t0 + 32) * 72 + c0 * 8] = k2r[1];
#pragma unroll
        for (int it = 0; it < 4; ++it)
            *(short8*)&Vts[b][(t0 + it * 32) * 72 + c0 * 8] = vr[it];
    };

    load_tile(0);
    store_tile(0);
    int p = 0;

    for (int kb = 0; kb < S_DIM / 64; ++kb) {
        __syncthreads();
        const bool more = (kb + 1 < S_DIM / 64);
        if (more) load_tile(kb + 1);

#pragma unroll
        for (int j = 0; j < 4; ++j) {
            f32x4 s1 = {0.f,0.f,0.f,0.f}, s2 = {0.f,0.f,0.f,0.f};
#pragma unroll
            for (int ks = 0; ks < 2; ++ks) {
                short8 k1 = *(const short8*)&K1s[p][(j * 16 + fr) * 72 + ks * 32 + qq * 8];
                short8 k2 = *(const short8*)&K2s[p][(j * 16 + fr) * 72 + ks * 32 + qq * 8];
                s1 = __builtin_amdgcn_mfma_f32_16x16x32_bf16(k1, q1f[ks], s1, 0, 0, 0);
                s2 = __builtin_amdgcn_mfma_f32_16x16x32_bf16(k2, q2f[ks], s2, 0, 0, 0);
            }
            float e1[4], e2[4];
#pragma unroll
            for (int r = 0; r < 4; ++r) {
                e1[r] = EXP2(s1[r]);            // Q pre-scaled by log2e
                e2[r] = EXP2(s2[r]);
                ls1 += e1[r]; ls2 += e2[r];
            }
            union { short4v s; unsigned u[2]; } P1, P2;
            P1.u[0] = pk_bf16(e1[0], e1[1]); P1.u[1] = pk_bf16(e1[2], e1[3]);
            P2.u[0] = pk_bf16(e2[0], e2[1]); P2.u[1] = pk_bf16(e2[2], e2[3]);
#pragma unroll
            for (int n = 0; n < 8; ++n) {
                short4v vf = *(const short4v*)&Vts[p][(n * 16 + fr) * 72 + j * 16 + qq * 4];
                a1[n] = __builtin_amdgcn_mfma_f32_16x16x16bf16_1k(vf, P1.s, a1[n], 0, 0, 0);
                a2[n] = __builtin_amdgcn_mfma_f32_16x16x16bf16_1k(vf, P2.s, a2[n], 0, 0, 0);
            }
        }

        if (more) store_tile(p ^ 1);
        p ^= 1;
    }

    float L1 = ls1, L2 = ls2;
    L1 += __shfl_xor(L1, 16, 64); L1 += __shfl_xor(L1, 32, 64);
    L2 += __shfl_xor(L2, 16, 64); L2 += __shfl_xor(L2, 32, 64);
    const float i1 = 1.f / L1, i2 = lam / L2;

    float o[8][4], sum = 0.f, sq = 0.f;
#pragma unroll
    for (int n = 0; n < 8; ++n)
#pragma unroll
        for (int r = 0; r < 4; ++r) {
            float v = a1[n][r] * i1 - a2[n][r] * i2;
            o[n][r] = v; sum += v; sq += v * v;
        }
    sum += __shfl_xor(sum, 16, 64); sum += __shfl_xor(sum, 32, 64);
    sq  += __shfl_xor(sq, 16, 64);  sq  += __shfl_xor(sq, 32, 64);
    const float mean = sum * (1.f / 128.f);
    const float var = sq * (1.f / 128.f) - mean * mean;
    const float inv = rsqrtf(var + 1e-5f);

    const long yrow = (long)(q0 + fr) * D_DIM + h * 128;
#pragma unroll
    for (int n = 0; n < 8; ++n) {
        float4 g4 = *(const float4*)&gw[h * 128 + n * 16 + qq * 4];
        float4 b4 = *(const float4*)&gb[h * 128 + n * 16 + qq * 4];
        ushort4 st;
        st.x = f2bf(((o[n][0] - mean) * inv * g4.x + b4.x) * 0.2f);
        st.y = f2bf(((o[n][1] - mean) * inv * g4.y + b4.y) * 0.2f);
        st.z = f2bf(((o[n][2] - mean) * inv * g4.z + b4.z) * 0.2f);
        st.w = f2bf(((o[n][3] - mean) * inv * g4.w + b4.w) * 0.2f);
        *(ushort4*)&Y[yrow + n * 16 + qq * 4] = st;
    }
}

// ---------------------------------------------------------------------------
extern "C" void kernel_launch(void* const* d_in, const int* in_sizes, int n_in,
                              void* d_out, int out_size, void* d_ws, size_t ws_size,
                              hipStream_t stream)
{
    const float* x   = (const float*)d_in[0];
    const float* Wq  = (const float*)d_in[1];
    const float* Wk  = (const float*)d_in[2];
    const float* Wv  = (const float*)d_in[3];
    const float* Wo  = (const float*)d_in[4];
    const float* lq1 = (const float*)d_in[5];
    const float* lk1 = (const float*)d_in[6];
    const float* lq2 = (const float*)d_in[7];
    const float* lk2 = (const float*)d_in[8];
    const float* gw  = (const float*)d_in[9];
    const float* gb  = (const float*)d_in[10];

    char* ws = (char*)d_ws;
    const size_t SEG = (size_t)D_DIM * D_DIM * sizeof(u16);   // 8 MiB
    const dim3 tgrid(32, 32), agrid(32, 16), ogrid(32, 16);

    if (ws_size >= 7 * SEG) {
        u16* XB  = (u16*)(ws + 0 * SEG);
        u16* WTq = (u16*)(ws + 1 * SEG);
        u16* WTk = (u16*)(ws + 2 * SEG);
        u16* WTv = (u16*)(ws + 3 * SEG);
        u16* Qb  = (u16*)(ws + 4 * SEG);
        u16* Kb  = (u16*)(ws + 5 * SEG);
        u16* Vt  = (u16*)(ws + 6 * SEG);
        u16* WTo = WTq;   // dead after QKV GEMM
        u16* Yb  = WTk;   // dead after QKV GEMM

        prep4<<<dim3(1024, 1, 4), 256, 0, stream>>>(x, Wq, Wk, Wv,
                                                    XB, WTq, WTk, WTv);
        gemm128<<<dim3(16, 16, 3), 256, 0, stream>>>(XB, WTq, WTk, WTv,
                                                     Qb, Kb, Vt, 0);
        transpose_fast<<<tgrid, 256, 0, stream>>>(Wo, WTo);
        diff_attn<<<agrid, 256, 0, stream>>>(Qb, Kb, Vt, lq1, lk1, lq2, lk2,
                                             gw, gb, Yb);
        gemm_out<<<ogrid, 256, 0, stream>>>(Yb, WTo, (float*)d_out);
    } else {
        u16* XB = (u16*)(ws + 0 * SEG);
        u16* WT = (u16*)(ws + 1 * SEG);
        u16* Qb = (u16*)(ws + 2 * SEG);
        u16* Kb = (u16*)(ws + 3 * SEG);
        u16* Vt = (u16*)(ws + 4 * SEG);

        cvt_bf16<<<4096, 256, 0, stream>>>(x, XB);
        transpose_fast<<<tgrid, 256, 0, stream>>>(Wq, WT);
        gemm128<<<dim3(16, 16, 1), 256, 0, stream>>>(XB, WT, WT, WT, Qb, Qb, Qb, 0);
        transpose_fast<<<tgrid, 256, 0, stream>>>(Wk, WT);
        gemm128<<<dim3(16, 16, 1), 256, 0, stream>>>(XB, WT, WT, WT, Kb, Kb, Kb, 1);
        transpose_fast<<<tgrid, 256, 0, stream>>>(Wv, WT);
        gemm128<<<dim3(16, 16, 1), 256, 0, stream>>>(XB, WT, WT, WT, Vt, Vt, Vt, 2);
        diff_attn<<<agrid, 256, 0, stream>>>(Qb, Kb, Vt, lq1, lk1, lq2, lk2,
                                             gw, gb, XB);
        transpose_fast<<<tgrid, 256, 0, stream>>>(Wo, WT);
        gemm_out<<<ogrid, 256, 0, stream>>>(XB, WT, (float*)d_out);
    }
}